// Round 12
// baseline (192.418 us; speedup 1.0000x reference)
//
#include <hip/hip_runtime.h>

// RAConv: reciprocal-attention graph conv, N=100K nodes, E=1.6M edges, D=64, fp32.
// CSR build -> wave-per-node register gather -> bf16 MFMA GEMM.
//   msg = (sum_e x_src*exp(logit)) / (sum_e exp(logit));  var = E[x^2]-E[x]^2
// R11: global-atomic-free CSR. R14: DPP dot reduce, gather 68->54.
// R16: 512-thread CSR + fsort LDS staging, 198us.
// R17: CSR collapsed to build+fsort (block-aggregated reservation, CAP=5120).
// R18: DIAGNOSTIC: top dispatch = harness 256MiB ws re-poison (~40us fixed).
// R19: single gather dispatch + build reg-caches dst/src: 190.5us (BEST).
// R15/R20/R21: three FAILED epilogue-reduce rewrites (same-operand permlane
//      swap; DPP row_bcast15/31 = not functional on gfx950; paired
//      permlane16/32_swap reduction identity wrong). ERRATA: on gfx950 use
//      only session-verified cross-lane prims (shfl_xor, quad_perm/row_ror
//      DPP). Epilogue optimization ABANDONED (3 strikes, ~5us upside).
// R22: verbatim revert of node_gather epilogue to R19 (combine4 shfl_xor,
//      lane<16 ushort4 writer). No other changes.

static inline size_t ws_align(size_t x) { return (x + 255) & ~size_t(255); }

typedef __attribute__((ext_vector_type(8))) short bf16x8;
typedef __attribute__((ext_vector_type(4))) float f32x4;
typedef __attribute__((ext_vector_type(2))) float f32x2;

#define ECHUNK 4096   // edges per build block
#define CAP    5120   // padded per-bucket capacity (and fsort LDS staging)
#define ESC    0.18033688f   // 0.125 * log2(e)

__device__ __forceinline__ unsigned short f2bf(float f) {
    unsigned u = __builtin_bit_cast(unsigned, f);
    u += 0x7FFFu + ((u >> 16) & 1u);          // RNE
    return (unsigned short)(u >> 16);
}
__device__ __forceinline__ float bfhi(int d) {          // high bf16 of dword
    return __builtin_bit_cast(float, (unsigned)d & 0xFFFF0000u);
}
__device__ __forceinline__ float bflo(int d) {          // low bf16 of dword
    return __builtin_bit_cast(float, (unsigned)d << 16);
}

__device__ __forceinline__ float fast_exp2(float t) {
#if __has_builtin(__builtin_amdgcn_exp2f)
    return __builtin_amdgcn_exp2f(t);
#else
    return exp2f(t);
#endif
}

// DPP add helper (VALU pipe only; bound_ctrl zeroes lanes with no source).
template <int CTRL>
__device__ __forceinline__ float dpp_radd(float t) {
    int v = __builtin_amdgcn_update_dpp(0, __builtin_bit_cast(int, t),
                                        CTRL, 0xF, 0xF, true);
    return t + __builtin_bit_cast(float, v);
}
// sum across each 16-lane row: quad_perm xor1 (0xB1), xor2 (0x4E) -> quad
// sums; row_ror:4 (0x124), row_ror:8 (0x128) -> all 16 lanes get row total.
// [session-verified on gfx950: R14 matched prediction, refchecked]
__device__ __forceinline__ float row16_sum(float t) {
    t = dpp_radd<0xB1>(t);
    t = dpp_radd<0x4E>(t);
    t = dpp_radd<0x124>(t);
    t = dpp_radd<0x128>(t);
    return t;
}

// sum across the 4 16-lane groups (session-verified shfl path).
__device__ __forceinline__ float combine4(float t) {
    t += __shfl_xor(t, 16, 64);
    t += __shfl_xor(t, 32, 64);
    return t;
}

// Fused: cast x->bf16 (grid-stride) AND one-pass bucket partition with
// block-aggregated reservation. Per block: LDS count over dst>>8 (dst+src
// cached in registers), one global atomicAdd per bucket reserves space,
// scatter packed (src<<8)|(dst&255) to tmp[b*CAP + base + rank].
// gcnt must be pre-zeroed.
__global__ void __launch_bounds__(512) build_kernel(
        const float* __restrict__ x, unsigned short* __restrict__ xb,
        const int* __restrict__ ei, int* __restrict__ gcnt,
        int* __restrict__ tmp, int E, int n4, int nb1) {
    __shared__ int cnt[512];                     // nb1 <= 512 (N <= 131072)
    __shared__ int base[512];
    int tid = threadIdx.x;
    for (int k = tid; k < nb1; k += 512) cnt[k] = 0;
    // cast part: grid-stride over n4 float4s
    int stride = gridDim.x * 512;
    for (int i = blockIdx.x * 512 + tid; i < n4; i += stride) {
        float4 v = ((const float4*)x)[i];
        ushort4 hh; hh.x = f2bf(v.x); hh.y = f2bf(v.y); hh.z = f2bf(v.z); hh.w = f2bf(v.w);
        ((ushort4*)xb)[i] = hh;
    }
    __syncthreads();
    const int* dstp = ei + E;
    int cbase = blockIdx.x * ECHUNK;
    int dcache[ECHUNK / 512];                    // 8 regs: dst per sub-iter
    int scache[ECHUNK / 512];                    // 8 regs: src per sub-iter
    #pragma unroll
    for (int k = 0; k < ECHUNK / 512; ++k) {
        int e = cbase + k * 512 + tid;
        int d = (e < E) ? dstp[e] : -1;
        dcache[k] = d;
        scache[k] = (e < E) ? ei[e] : 0;
        if (d >= 0) atomicAdd(&cnt[d >> 8], 1);
    }
    __syncthreads();
    for (int k = tid; k < nb1; k += 512) {
        int c = cnt[k];
        base[k] = c ? atomicAdd(&gcnt[k], c) : 0;   // block-level reservation
        cnt[k] = 0;                                  // reuse as rank counter
    }
    __syncthreads();
    #pragma unroll
    for (int k = 0; k < ECHUNK / 512; ++k) {
        int dst = dcache[k];
        if (dst >= 0) {
            int b = dst >> 8;
            int r = base[b] + atomicAdd(&cnt[b], 1);
            if (r < CAP)                             // overflow guard (never hit)
                tmp[b * CAP + r] = (scache[k] << 8) | (dst & 255);
        }
    }
}

// Per-bucket fine sort: one block per bucket (256 nodes), 512 threads.
// Segment [b*CAP, b*CAP+gcnt[b]) staged once into LDS; 256-bin hist + scan
// -> writes per-node bounds rs/re, scatters srcs in node order.
__global__ void __launch_bounds__(512) fsort_kernel(
        const int* __restrict__ tmp, const int* __restrict__ gcnt,
        int* __restrict__ srcs, int* __restrict__ rs, int* __restrict__ re,
        int N, int nb1) {
    __shared__ int cnt[256], sc[256], lofs[256];
    __shared__ int stage[CAP];
    int b = blockIdx.x, tid = threadIdx.x;
    int start = b * CAP;
    int seg = min(gcnt[b], CAP);

    if (tid < 256) cnt[tid] = 0;
    for (int k = tid; k < seg; k += 512) stage[k] = tmp[start + k];
    __syncthreads();
    for (int k = tid; k < seg; k += 512) atomicAdd(&cnt[stage[k] & 255], 1);
    __syncthreads();
    int c = (tid < 256) ? cnt[tid] : 0;
    if (tid < 256) sc[tid] = c;
    __syncthreads();
    for (int off = 1; off < 256; off <<= 1) {
        int u = (tid < 256 && tid >= off) ? sc[tid - off] : 0;
        __syncthreads();
        if (tid < 256) sc[tid] += u;
        __syncthreads();
    }
    if (tid < 256) {
        int excl = sc[tid] - c;
        int node = b * 256 + tid;
        if (node < N) { rs[node] = start + excl; re[node] = start + excl + c; }
        lofs[tid] = start + excl;
    }
    __syncthreads();
    for (int k = tid; k < seg; k += 512) {
        int v = stage[k];
        int pos = atomicAdd(&lofs[v & 255], 1);
        srcs[pos] = v >> 8;
    }
}

// One wave per node, 4 edges per batch: 16-lane group g handles one edge,
// lane q=lane&15 holds features 4q..4q+3 as two float2 (packed-fp32 path).
// xn pre-scaled by 0.125*log2e so the dot is already in exp2 units.
// srcs preloaded 64/chunk, indices via __shfl; xb gathers double-buffered;
// dot reduce via DPP; cross-group combine via shfl_xor (R19-verified);
// bounds from rs/re (padded CSR).
__global__ void __launch_bounds__(256) node_gather_kernel(
        const unsigned short* __restrict__ xb,
        const int* __restrict__ rs, const int* __restrict__ re,
        const int* __restrict__ srcs,
        unsigned short* __restrict__ msgvar, int N) {
    int w = (blockIdx.x * blockDim.x + threadIdx.x) >> 6;
    if (w >= N) return;
    int lane = threadIdx.x & 63;
    int q = lane & 15;                 // feature block (features 4q..4q+3)
    int g = lane >> 4;                 // edge slot within batch of 4
    int s = rs[w], e = re[w];
    const int2* xb2 = (const int2*)xb;            // row = 16 int2 (128 B)
    int2 dn = xb2[(size_t)w * 16 + q];
    f32x2 esc2 = {ESC, ESC};
    f32x2 xn01 = {bflo(dn.x), bfhi(dn.x)}, xn23 = {bflo(dn.y), bfhi(dn.y)};
    xn01 *= esc2; xn23 *= esc2;                   // fold softmax scale + log2e
    float den = 0.f;
    f32x2 sxa = {0,0}, sxb = {0,0}, ssqa = {0,0}, ssqb = {0,0},
          smea = {0,0}, smeb = {0,0};

    auto compute = [&](int2 d) {
        f32x2 a = {bflo(d.x), bfhi(d.x)};
        f32x2 b = {bflo(d.y), bfhi(d.y)};
        f32x2 dp = a * xn01 + b * xn23;           // pk mul + pk fma
        float t = row16_sum(dp.x + dp.y);         // DPP reduce, VALU-only
        float ex = fast_exp2(t);
        f32x2 ex2 = {ex, ex};
        den += ex;
        sxa += a;           sxb += b;             // pk add
        ssqa += a * a;      ssqb += b * b;        // pk fma
        smea += ex2 * a;    smeb += ex2 * b;      // pk fma
    };

    for (int base = s; base < e; base += 64) {    // chunk of <=64 edges
        int cnt = min(e - base, 64);
        // one coalesced load: lane holds srcs[base+lane] (clamped)
        int idx = srcs[base + min(lane, cnt - 1)];
        int p = 0;
        int2 da, db;
        if (p + 8 <= cnt) {                       // prologue: loads for batch 0
            int ra = __shfl(idx, p + g, 64);
            int rb = __shfl(idx, p + 4 + g, 64);
            da = xb2[(size_t)ra * 16 + q];
            db = xb2[(size_t)rb * 16 + q];
        }
        for (; p + 16 <= cnt; p += 8) {           // steady state: prefetch next
            int ra1 = __shfl(idx, p + 8 + g, 64);
            int rb1 = __shfl(idx, p + 12 + g, 64);
            int2 da1 = xb2[(size_t)ra1 * 16 + q];
            int2 db1 = xb2[(size_t)rb1 * 16 + q];
            compute(da);
            compute(db);
            da = da1; db = db1;
        }
        if (p + 8 <= cnt) {                       // drain
            compute(da);
            compute(db);
            p += 8;
        }
        for (; p < cnt; p += 4) {                 // masked tail (<=2 iters)
            float wt = (p + g < cnt) ? 1.f : 0.f;
            int r = __shfl(idx, min(p + g, cnt - 1), 64);
            int2 d = xb2[(size_t)r * 16 + q];
            f32x2 a = {bflo(d.x), bfhi(d.x)};
            f32x2 b = {bflo(d.y), bfhi(d.y)};
            f32x2 dp = a * xn01 + b * xn23;
            float t = row16_sum(dp.x + dp.y);
            float ex = fast_exp2(t) * wt;
            f32x2 wt2 = {wt, wt}, ex2 = {ex, ex};
            f32x2 wa = a * wt2, wb = b * wt2;
            den += ex;
            sxa += wa;          sxb += wb;
            ssqa += wa * a;     ssqb += wb * b;
            smea += ex2 * a;    smeb += ex2 * b;
        }
    }
    // combine the 4 groups (lanes q, q+16, q+32, q+48 hold the same features)
    den    = combine4(den);
    sxa.x  = combine4(sxa.x);  sxa.y  = combine4(sxa.y);
    sxb.x  = combine4(sxb.x);  sxb.y  = combine4(sxb.y);
    ssqa.x = combine4(ssqa.x); ssqa.y = combine4(ssqa.y);
    ssqb.x = combine4(ssqb.x); ssqb.y = combine4(ssqb.y);
    smea.x = combine4(smea.x); smea.y = combine4(smea.y);
    smeb.x = combine4(smeb.x); smeb.y = combine4(smeb.y);
    if (lane < 16) {
        float inv = 1.f / fmaxf((float)(e - s), 1.f);
        float invden = (den > 0.f) ? (1.f / den) : 0.f;
        float m0 = sxa.x * inv, m1 = sxa.y * inv, m2 = sxb.x * inv, m3 = sxb.y * inv;
        ushort4 hm, hv;
        hm.x = f2bf(smea.x * invden); hm.y = f2bf(smea.y * invden);
        hm.z = f2bf(smeb.x * invden); hm.w = f2bf(smeb.y * invden);
        hv.x = f2bf(ssqa.x * inv - m0 * m0); hv.y = f2bf(ssqa.y * inv - m1 * m1);
        hv.z = f2bf(ssqb.x * inv - m2 * m2); hv.w = f2bf(ssqb.y * inv - m3 * m3);
        *(ushort4*)&msgvar[(size_t)w * 128 + 4 * q]      = hm;
        *(ushort4*)&msgvar[(size_t)w * 128 + 64 + 4 * q] = hv;
    }
}

// MFMA epilogue GEMM: out = A @ Wcat^T + b, A = [x | msg | var] (N x 192),
// all inputs already bf16 (xb, msgvar). 2 node-tiles of 64 per block with
// W-fragments and bias resident in registers across tiles.
__global__ void __launch_bounds__(256) gemm_kernel(
        const unsigned short* __restrict__ xb, const unsigned short* __restrict__ msgvar,
        const float* __restrict__ Ws, const float* __restrict__ bs,
        const float* __restrict__ Wn, const float* __restrict__ bn,
        const float* __restrict__ Wv, const float* __restrict__ bv,
        float* __restrict__ out, int N) {
    __shared__ unsigned short As[64 * 200];
    int tid = threadIdx.x;
    int lane = tid & 63;
    int wv = tid >> 6;                  // feature tile (wave id)
    int j = lane & 15, quad = lane >> 4;
    int jg = wv * 16 + j;               // global output feature

    // B fragments: 6 K-steps, lane holds W[jg][k0..k0+7] as bf16
    const float* Wm0[3] = {Ws, Wn, Wv};
    bf16x8 bfrag[6];
    #pragma unroll
    for (int ks = 0; ks < 6; ++ks) {
        const float* W = Wm0[ks >> 1];
        int k0 = (ks & 1) * 32 + quad * 8;
        const float4* p = (const float4*)(W + (size_t)jg * 64 + k0);
        float4 a = p[0], b = p[1];
        bf16x8 f;
        f[0] = (short)f2bf(a.x); f[1] = (short)f2bf(a.y);
        f[2] = (short)f2bf(a.z); f[3] = (short)f2bf(a.w);
        f[4] = (short)f2bf(b.x); f[5] = (short)f2bf(b.y);
        f[6] = (short)f2bf(b.z); f[7] = (short)f2bf(b.w);
        bfrag[ks] = f;
    }
    float bias = bs[jg] + bn[jg] + bv[jg];

    #pragma unroll
    for (int t = 0; t < 2; ++t) {
        int nbase = blockIdx.x * 128 + t * 64;
        // stage x part from xb: 64 rows x 16 ushort4 (bf16 direct copy)
        #pragma unroll
        for (int i = 0; i < 4; ++i) {
            int idx = i * 256 + tid;
            int row = idx >> 4, c = idx & 15;
            int n = min(nbase + row, N - 1);
            ushort4 h = ((const ushort4*)(xb + (size_t)n * 64))[c];
            *(ushort4*)&As[row * 200 + c * 4] = h;
        }
        // stage msgvar part: 64 rows x 32 ushort4 (bf16, [msg|var] contiguous)
        #pragma unroll
        for (int i = 0; i < 8; ++i) {
            int idx = i * 256 + tid;
            int row = idx >> 5, c = idx & 31;
            int n = min(nbase + row, N - 1);
            ushort4 h = ((const ushort4*)(msgvar + (size_t)n * 128))[c];
            *(ushort4*)&As[row * 200 + 64 + c * 4] = h;
        }
        __syncthreads();

        f32x4 acc[4];
        #pragma unroll
        for (int nt = 0; nt < 4; ++nt) {
            acc[nt][0] = bias; acc[nt][1] = bias; acc[nt][2] = bias; acc[nt][3] = bias;
        }
        #pragma unroll
        for (int nt = 0; nt < 4; ++nt) {
            #pragma unroll
            for (int ks = 0; ks < 6; ++ks) {
                const bf16x8* ap = (const bf16x8*)&As[(nt * 16 + j) * 200 + ks * 32 + quad * 8];
                acc[nt] = __builtin_amdgcn_mfma_f32_16x16x32_bf16(*ap, bfrag[ks], acc[nt], 0, 0, 0);
            }
        }
        // D: node = nbase + nt*16 + quad*4 + r, col = jg
        #pragma unroll
        for (int nt = 0; nt < 4; ++nt) {
            #pragma unroll
            for (int r = 0; r < 4; ++r) {
                int node = nbase + nt * 16 + quad * 4 + r;
                if (node < N) out[(size_t)node * 64 + jg] = acc[nt][r];
            }
        }
        __syncthreads();   // protect As before next tile's staging
    }
}

extern "C" void kernel_launch(void* const* d_in, const int* in_sizes, int n_in,
                              void* d_out, int out_size, void* d_ws, size_t ws_size,
                              hipStream_t stream) {
    const float* x  = (const float*)d_in[0];
    const int*   ei = (const int*)d_in[1];
    const float* Ws = (const float*)d_in[2];
    const float* bs = (const float*)d_in[3];
    const float* Wn = (const float*)d_in[4];
    const float* bn = (const float*)d_in[5];
    const float* Wv = (const float*)d_in[6];
    const float* bv = (const float*)d_in[7];
    float* out = (float*)d_out;

    int N  = in_sizes[0] / 64;
    int E  = in_sizes[1] / 2;
    int nblk = (E + ECHUNK - 1) / ECHUNK;        // build blocks
    int nb1  = (N + 255) >> 8;                   // coarse buckets (<= 512)

    char* wsp = (char*)d_ws;
    size_t off = 0;
    int* gcnt   = (int*)(wsp + off); off += ws_align((size_t)nb1 * 4);
    int* rs     = (int*)(wsp + off); off += ws_align((size_t)N * 4);
    int* re     = (int*)(wsp + off); off += ws_align((size_t)N * 4);
    int* tmp    = (int*)(wsp + off); off += ws_align((size_t)nb1 * CAP * 4);
    int* srcs   = (int*)(wsp + off); off += ws_align((size_t)nb1 * CAP * 4);
    unsigned short* msgvar = (unsigned short*)(wsp + off); off += ws_align((size_t)N * 128 * 2);
    unsigned short* xb     = (unsigned short*)(wsp + off); off += ws_align((size_t)N * 64 * 2);

    int n4 = N * 16;
    hipMemsetAsync(gcnt, 0, (size_t)nb1 * 4, stream);
    build_kernel<<<nblk, 512, 0, stream>>>(x, xb, ei, gcnt, tmp, E, n4, nb1);
    fsort_kernel<<<nb1, 512, 0, stream>>>(tmp, gcnt, srcs, rs, re, N, nb1);
    node_gather_kernel<<<((size_t)N * 64 + 255) / 256, 256, 0, stream>>>(xb, rs, re, srcs, msgvar, N);
    gemm_kernel<<<(N + 127) / 128, 256, 0, stream>>>(xb, msgvar, Ws, bs, Wn, bn, Wv, bv, out, N);
}

// Round 13
// 178.130 us; speedup vs baseline: 1.0802x; 1.0802x over previous
//
#include <hip/hip_runtime.h>

// RAConv: reciprocal-attention graph conv, N=100K nodes, E=1.6M edges, D=64, fp32.
// CSR build -> wave-per-node register gather -> bf16 MFMA GEMM.
//   msg = (sum_e x_src*exp(logit)) / (sum_e exp(logit));  var = E[x^2]-E[x]^2
// R11: global-atomic-free CSR. R14: DPP dot reduce, gather 68->54.
// R16: 512-thread CSR + fsort LDS staging. R17: CSR -> build+fsort (CAP=5120).
// R18: DIAGNOSTIC: harness 256MiB ws re-poison = ~40us/iter fixed tax.
// R19: build reg-caches dst/src: 190.5us. R22: revert to R19 state (192.4).
// R15/R20/R21: three FAILED epilogue-reduce rewrites. ERRATA: use only
//      session-verified cross-lane prims (shfl, shfl_xor, quad_perm/row_ror).
// R23: TWO NODES PER WAVE (lanes 0-31 node 2i, lanes 32-63 node 2i+1;
//      16 feature-lanes x 2 edge slots per half). Amortizes the per-node
//      fixed cost: combine = ONE shfl_xor(16) level per value (xor16 never
//      crosses the 32-lane boundary) = 13 issues/node vs 52; final math +
//      stores concurrent across halves; tail waste halves. Cost: loop runs
//      max(degA,degB)/2 batches (+~14%, Poisson pairing) with exec-masked
//      half-divergence. Only verified primitives.

static inline size_t ws_align(size_t x) { return (x + 255) & ~size_t(255); }

typedef __attribute__((ext_vector_type(8))) short bf16x8;
typedef __attribute__((ext_vector_type(4))) float f32x4;
typedef __attribute__((ext_vector_type(2))) float f32x2;

#define ECHUNK 4096   // edges per build block
#define CAP    5120   // padded per-bucket capacity (and fsort LDS staging)
#define ESC    0.18033688f   // 0.125 * log2(e)

__device__ __forceinline__ unsigned short f2bf(float f) {
    unsigned u = __builtin_bit_cast(unsigned, f);
    u += 0x7FFFu + ((u >> 16) & 1u);          // RNE
    return (unsigned short)(u >> 16);
}
__device__ __forceinline__ float bfhi(int d) {          // high bf16 of dword
    return __builtin_bit_cast(float, (unsigned)d & 0xFFFF0000u);
}
__device__ __forceinline__ float bflo(int d) {          // low bf16 of dword
    return __builtin_bit_cast(float, (unsigned)d << 16);
}

__device__ __forceinline__ float fast_exp2(float t) {
#if __has_builtin(__builtin_amdgcn_exp2f)
    return __builtin_amdgcn_exp2f(t);
#else
    return exp2f(t);
#endif
}

// DPP add helper (VALU pipe only; bound_ctrl zeroes lanes with no source).
template <int CTRL>
__device__ __forceinline__ float dpp_radd(float t) {
    int v = __builtin_amdgcn_update_dpp(0, __builtin_bit_cast(int, t),
                                        CTRL, 0xF, 0xF, true);
    return t + __builtin_bit_cast(float, v);
}
// sum across each 16-lane row: quad_perm xor1 (0xB1), xor2 (0x4E) -> quad
// sums; row_ror:4 (0x124), row_ror:8 (0x128) -> all 16 lanes get row total.
// [session-verified on gfx950: R14 matched prediction, refchecked]
__device__ __forceinline__ float row16_sum(float t) {
    t = dpp_radd<0xB1>(t);
    t = dpp_radd<0x4E>(t);
    t = dpp_radd<0x124>(t);
    t = dpp_radd<0x128>(t);
    return t;
}

// combine the 2 groups of a 32-lane half (xor16 stays within the half).
__device__ __forceinline__ float combine2(float t) {
    t += __shfl_xor(t, 16, 64);
    return t;
}

// Fused: cast x->bf16 (grid-stride) AND one-pass bucket partition with
// block-aggregated reservation. Per block: LDS count over dst>>8 (dst+src
// cached in registers), one global atomicAdd per bucket reserves space,
// scatter packed (src<<8)|(dst&255) to tmp[b*CAP + base + rank].
// gcnt must be pre-zeroed.
__global__ void __launch_bounds__(512) build_kernel(
        const float* __restrict__ x, unsigned short* __restrict__ xb,
        const int* __restrict__ ei, int* __restrict__ gcnt,
        int* __restrict__ tmp, int E, int n4, int nb1) {
    __shared__ int cnt[512];                     // nb1 <= 512 (N <= 131072)
    __shared__ int base[512];
    int tid = threadIdx.x;
    for (int k = tid; k < nb1; k += 512) cnt[k] = 0;
    // cast part: grid-stride over n4 float4s
    int stride = gridDim.x * 512;
    for (int i = blockIdx.x * 512 + tid; i < n4; i += stride) {
        float4 v = ((const float4*)x)[i];
        ushort4 hh; hh.x = f2bf(v.x); hh.y = f2bf(v.y); hh.z = f2bf(v.z); hh.w = f2bf(v.w);
        ((ushort4*)xb)[i] = hh;
    }
    __syncthreads();
    const int* dstp = ei + E;
    int cbase = blockIdx.x * ECHUNK;
    int dcache[ECHUNK / 512];                    // 8 regs: dst per sub-iter
    int scache[ECHUNK / 512];                    // 8 regs: src per sub-iter
    #pragma unroll
    for (int k = 0; k < ECHUNK / 512; ++k) {
        int e = cbase + k * 512 + tid;
        int d = (e < E) ? dstp[e] : -1;
        dcache[k] = d;
        scache[k] = (e < E) ? ei[e] : 0;
        if (d >= 0) atomicAdd(&cnt[d >> 8], 1);
    }
    __syncthreads();
    for (int k = tid; k < nb1; k += 512) {
        int c = cnt[k];
        base[k] = c ? atomicAdd(&gcnt[k], c) : 0;   // block-level reservation
        cnt[k] = 0;                                  // reuse as rank counter
    }
    __syncthreads();
    #pragma unroll
    for (int k = 0; k < ECHUNK / 512; ++k) {
        int dst = dcache[k];
        if (dst >= 0) {
            int b = dst >> 8;
            int r = base[b] + atomicAdd(&cnt[b], 1);
            if (r < CAP)                             // overflow guard (never hit)
                tmp[b * CAP + r] = (scache[k] << 8) | (dst & 255);
        }
    }
}

// Per-bucket fine sort: one block per bucket (256 nodes), 512 threads.
// Segment [b*CAP, b*CAP+gcnt[b]) staged once into LDS; 256-bin hist + scan
// -> writes per-node bounds rs/re, scatters srcs in node order.
__global__ void __launch_bounds__(512) fsort_kernel(
        const int* __restrict__ tmp, const int* __restrict__ gcnt,
        int* __restrict__ srcs, int* __restrict__ rs, int* __restrict__ re,
        int N, int nb1) {
    __shared__ int cnt[256], sc[256], lofs[256];
    __shared__ int stage[CAP];
    int b = blockIdx.x, tid = threadIdx.x;
    int start = b * CAP;
    int seg = min(gcnt[b], CAP);

    if (tid < 256) cnt[tid] = 0;
    for (int k = tid; k < seg; k += 512) stage[k] = tmp[start + k];
    __syncthreads();
    for (int k = tid; k < seg; k += 512) atomicAdd(&cnt[stage[k] & 255], 1);
    __syncthreads();
    int c = (tid < 256) ? cnt[tid] : 0;
    if (tid < 256) sc[tid] = c;
    __syncthreads();
    for (int off = 1; off < 256; off <<= 1) {
        int u = (tid < 256 && tid >= off) ? sc[tid - off] : 0;
        __syncthreads();
        if (tid < 256) sc[tid] += u;
        __syncthreads();
    }
    if (tid < 256) {
        int excl = sc[tid] - c;
        int node = b * 256 + tid;
        if (node < N) { rs[node] = start + excl; re[node] = start + excl + c; }
        lofs[tid] = start + excl;
    }
    __syncthreads();
    for (int k = tid; k < seg; k += 512) {
        int v = stage[k];
        int pos = atomicAdd(&lofs[v & 255], 1);
        srcs[pos] = v >> 8;
    }
}

// Two nodes per wave (R23): lanes 0-31 node 2i, lanes 32-63 node 2i+1.
// Within a half: lane q=hl&15 holds features 4q..4q+3; g=hl>>4 is the edge
// slot (2 per batch). xn pre-scaled by 0.125*log2e (exp2 direct). srcs
// preloaded 32/chunk per half; indices via __shfl width=32; xb gathers
// double-buffered; dot reduce via row16_sum DPP; cross-group combine =
// one shfl_xor(16) (never crosses the 32-lane boundary).
__global__ void __launch_bounds__(256) node_gather_kernel(
        const unsigned short* __restrict__ xb,
        const int* __restrict__ rs, const int* __restrict__ re,
        const int* __restrict__ srcs,
        unsigned short* __restrict__ msgvar, int N) {
    int pair = (blockIdx.x * blockDim.x + threadIdx.x) >> 6;
    if (pair * 2 >= N) return;
    int lane = threadIdx.x & 63;
    int half = lane >> 5;              // 0: node 2i, 1: node 2i+1
    int hl = lane & 31;                // lane within half
    int q = hl & 15;                   // feature block (features 4q..4q+3)
    int g = hl >> 4;                   // edge slot within batch of 2
    int w = pair * 2 + half;
    bool valid = (w < N);
    int s = 0, e = 0;
    if (valid) { s = rs[w]; e = re[w]; }
    const int2* xb2 = (const int2*)xb;            // row = 16 int2 (128 B)
    int wc = min(w, N - 1);
    int2 dn = xb2[(size_t)wc * 16 + q];
    f32x2 esc2 = {ESC, ESC};
    f32x2 xn01 = {bflo(dn.x), bfhi(dn.x)}, xn23 = {bflo(dn.y), bfhi(dn.y)};
    xn01 *= esc2; xn23 *= esc2;                   // fold softmax scale + log2e
    float den = 0.f;
    f32x2 sxa = {0,0}, sxb = {0,0}, ssqa = {0,0}, ssqb = {0,0},
          smea = {0,0}, smeb = {0,0};

    auto compute = [&](int2 d) {
        f32x2 a = {bflo(d.x), bfhi(d.x)};
        f32x2 b = {bflo(d.y), bfhi(d.y)};
        f32x2 dp = a * xn01 + b * xn23;           // pk mul + pk fma
        float t = row16_sum(dp.x + dp.y);         // DPP reduce, VALU-only
        float ex = fast_exp2(t);
        f32x2 ex2 = {ex, ex};
        den += ex;
        sxa += a;           sxb += b;             // pk add
        ssqa += a * a;      ssqb += b * b;        // pk fma
        smea += ex2 * a;    smeb += ex2 * b;      // pk fma
    };

    for (int base = s; base < e; base += 32) {    // chunk of <=32 edges (half)
        int cnt = min(e - base, 32);
        // one coalesced load per half: lane holds srcs[base+hl] (clamped)
        int idx = srcs[base + min(hl, cnt - 1)];
        int p = 0;
        int2 da, db;
        if (p + 4 <= cnt) {                       // prologue: 2 batches of 2
            int ra = __shfl(idx, p + g, 32);
            int rb = __shfl(idx, p + 2 + g, 32);
            da = xb2[(size_t)ra * 16 + q];
            db = xb2[(size_t)rb * 16 + q];
        }
        for (; p + 8 <= cnt; p += 4) {            // steady state: prefetch next
            int ra1 = __shfl(idx, p + 4 + g, 32);
            int rb1 = __shfl(idx, p + 6 + g, 32);
            int2 da1 = xb2[(size_t)ra1 * 16 + q];
            int2 db1 = xb2[(size_t)rb1 * 16 + q];
            compute(da);
            compute(db);
            da = da1; db = db1;
        }
        if (p + 4 <= cnt) {                       // drain
            compute(da);
            compute(db);
            p += 4;
        }
        for (; p < cnt; p += 2) {                 // masked tail (<=2 iters)
            float wt = (p + g < cnt) ? 1.f : 0.f;
            int r = __shfl(idx, min(p + g, cnt - 1), 32);
            int2 d = xb2[(size_t)r * 16 + q];
            f32x2 a = {bflo(d.x), bfhi(d.x)};
            f32x2 b = {bflo(d.y), bfhi(d.y)};
            f32x2 dp = a * xn01 + b * xn23;
            float t = row16_sum(dp.x + dp.y);
            float ex = fast_exp2(t) * wt;
            f32x2 wt2 = {wt, wt}, ex2 = {ex, ex};
            f32x2 wa = a * wt2, wb = b * wt2;
            den += ex;
            sxa += wa;          sxb += wb;
            ssqa += wa * a;     ssqb += wb * b;
            smea += ex2 * a;    smeb += ex2 * b;
        }
    }
    // combine the 2 groups of this half (lanes q and q+16 hold same features)
    den    = combine2(den);
    sxa.x  = combine2(sxa.x);  sxa.y  = combine2(sxa.y);
    sxb.x  = combine2(sxb.x);  sxb.y  = combine2(sxb.y);
    ssqa.x = combine2(ssqa.x); ssqa.y = combine2(ssqa.y);
    ssqb.x = combine2(ssqb.x); ssqb.y = combine2(ssqb.y);
    smea.x = combine2(smea.x); smea.y = combine2(smea.y);
    smeb.x = combine2(smeb.x); smeb.y = combine2(smeb.y);
    if (valid && hl < 16) {
        float inv = 1.f / fmaxf((float)(e - s), 1.f);
        float invden = (den > 0.f) ? (1.f / den) : 0.f;
        float m0 = sxa.x * inv, m1 = sxa.y * inv, m2 = sxb.x * inv, m3 = sxb.y * inv;
        ushort4 hm, hv;
        hm.x = f2bf(smea.x * invden); hm.y = f2bf(smea.y * invden);
        hm.z = f2bf(smeb.x * invden); hm.w = f2bf(smeb.y * invden);
        hv.x = f2bf(ssqa.x * inv - m0 * m0); hv.y = f2bf(ssqa.y * inv - m1 * m1);
        hv.z = f2bf(ssqb.x * inv - m2 * m2); hv.w = f2bf(ssqb.y * inv - m3 * m3);
        *(ushort4*)&msgvar[(size_t)w * 128 + 4 * q]      = hm;
        *(ushort4*)&msgvar[(size_t)w * 128 + 64 + 4 * q] = hv;
    }
}

// MFMA epilogue GEMM: out = A @ Wcat^T + b, A = [x | msg | var] (N x 192),
// all inputs already bf16 (xb, msgvar). 2 node-tiles of 64 per block with
// W-fragments and bias resident in registers across tiles.
__global__ void __launch_bounds__(256) gemm_kernel(
        const unsigned short* __restrict__ xb, const unsigned short* __restrict__ msgvar,
        const float* __restrict__ Ws, const float* __restrict__ bs,
        const float* __restrict__ Wn, const float* __restrict__ bn,
        const float* __restrict__ Wv, const float* __restrict__ bv,
        float* __restrict__ out, int N) {
    __shared__ unsigned short As[64 * 200];
    int tid = threadIdx.x;
    int lane = tid & 63;
    int wv = tid >> 6;                  // feature tile (wave id)
    int j = lane & 15, quad = lane >> 4;
    int jg = wv * 16 + j;               // global output feature

    // B fragments: 6 K-steps, lane holds W[jg][k0..k0+7] as bf16
    const float* Wm0[3] = {Ws, Wn, Wv};
    bf16x8 bfrag[6];
    #pragma unroll
    for (int ks = 0; ks < 6; ++ks) {
        const float* W = Wm0[ks >> 1];
        int k0 = (ks & 1) * 32 + quad * 8;
        const float4* p = (const float4*)(W + (size_t)jg * 64 + k0);
        float4 a = p[0], b = p[1];
        bf16x8 f;
        f[0] = (short)f2bf(a.x); f[1] = (short)f2bf(a.y);
        f[2] = (short)f2bf(a.z); f[3] = (short)f2bf(a.w);
        f[4] = (short)f2bf(b.x); f[5] = (short)f2bf(b.y);
        f[6] = (short)f2bf(b.z); f[7] = (short)f2bf(b.w);
        bfrag[ks] = f;
    }
    float bias = bs[jg] + bn[jg] + bv[jg];

    #pragma unroll
    for (int t = 0; t < 2; ++t) {
        int nbase = blockIdx.x * 128 + t * 64;
        // stage x part from xb: 64 rows x 16 ushort4 (bf16 direct copy)
        #pragma unroll
        for (int i = 0; i < 4; ++i) {
            int idx = i * 256 + tid;
            int row = idx >> 4, c = idx & 15;
            int n = min(nbase + row, N - 1);
            ushort4 h = ((const ushort4*)(xb + (size_t)n * 64))[c];
            *(ushort4*)&As[row * 200 + c * 4] = h;
        }
        // stage msgvar part: 64 rows x 32 ushort4 (bf16, [msg|var] contiguous)
        #pragma unroll
        for (int i = 0; i < 8; ++i) {
            int idx = i * 256 + tid;
            int row = idx >> 5, c = idx & 31;
            int n = min(nbase + row, N - 1);
            ushort4 h = ((const ushort4*)(msgvar + (size_t)n * 128))[c];
            *(ushort4*)&As[row * 200 + 64 + c * 4] = h;
        }
        __syncthreads();

        f32x4 acc[4];
        #pragma unroll
        for (int nt = 0; nt < 4; ++nt) {
            acc[nt][0] = bias; acc[nt][1] = bias; acc[nt][2] = bias; acc[nt][3] = bias;
        }
        #pragma unroll
        for (int nt = 0; nt < 4; ++nt) {
            #pragma unroll
            for (int ks = 0; ks < 6; ++ks) {
                const bf16x8* ap = (const bf16x8*)&As[(nt * 16 + j) * 200 + ks * 32 + quad * 8];
                acc[nt] = __builtin_amdgcn_mfma_f32_16x16x32_bf16(*ap, bfrag[ks], acc[nt], 0, 0, 0);
            }
        }
        // D: node = nbase + nt*16 + quad*4 + r, col = jg
        #pragma unroll
        for (int nt = 0; nt < 4; ++nt) {
            #pragma unroll
            for (int r = 0; r < 4; ++r) {
                int node = nbase + nt * 16 + quad * 4 + r;
                if (node < N) out[(size_t)node * 64 + jg] = acc[nt][r];
            }
        }
        __syncthreads();   // protect As before next tile's staging
    }
}

extern "C" void kernel_launch(void* const* d_in, const int* in_sizes, int n_in,
                              void* d_out, int out_size, void* d_ws, size_t ws_size,
                              hipStream_t stream) {
    const float* x  = (const float*)d_in[0];
    const int*   ei = (const int*)d_in[1];
    const float* Ws = (const float*)d_in[2];
    const float* bs = (const float*)d_in[3];
    const float* Wn = (const float*)d_in[4];
    const float* bn = (const float*)d_in[5];
    const float* Wv = (const float*)d_in[6];
    const float* bv = (const float*)d_in[7];
    float* out = (float*)d_out;

    int N  = in_sizes[0] / 64;
    int E  = in_sizes[1] / 2;
    int nblk = (E + ECHUNK - 1) / ECHUNK;        // build blocks
    int nb1  = (N + 255) >> 8;                   // coarse buckets (<= 512)

    char* wsp = (char*)d_ws;
    size_t off = 0;
    int* gcnt   = (int*)(wsp + off); off += ws_align((size_t)nb1 * 4);
    int* rs     = (int*)(wsp + off); off += ws_align((size_t)N * 4);
    int* re     = (int*)(wsp + off); off += ws_align((size_t)N * 4);
    int* tmp    = (int*)(wsp + off); off += ws_align((size_t)nb1 * CAP * 4);
    int* srcs   = (int*)(wsp + off); off += ws_align((size_t)nb1 * CAP * 4);
    unsigned short* msgvar = (unsigned short*)(wsp + off); off += ws_align((size_t)N * 128 * 2);
    unsigned short* xb     = (unsigned short*)(wsp + off); off += ws_align((size_t)N * 64 * 2);

    int n4 = N * 16;
    hipMemsetAsync(gcnt, 0, (size_t)nb1 * 4, stream);
    build_kernel<<<nblk, 512, 0, stream>>>(x, xb, ei, gcnt, tmp, E, n4, nb1);
    fsort_kernel<<<nb1, 512, 0, stream>>>(tmp, gcnt, srcs, rs, re, N, nb1);
    int npair = (N + 1) / 2;                     // two nodes per wave (R23)
    node_gather_kernel<<<((size_t)npair * 64 + 255) / 256, 256, 0, stream>>>(
        xb, rs, re, srcs, msgvar, N);
    gemm_kernel<<<(N + 127) / 128, 256, 0, stream>>>(xb, msgvar, Ws, bs, Wn, bn, Wv, bv, out, N);
}